// Round 1
// baseline (2025.335 us; speedup 1.0000x reference)
//
#include <hip/hip_runtime.h>
#include <hip/hip_bf16.h>
#include <math.h>

// Problem constants
#define Bn 2
#define Sn 2048
#define Dn 1024
#define Hn 16
#define DKn 64

// ---------------- GEMM: C[M][N] = A[M][K] * B[N][K] + bias[N] ----------------
// (reference does x @ W.T, so both A and W are K-contiguous -> "NT" gemm)
#define TILE 64
#define KTILE 16

__global__ __launch_bounds__(256) void gemm_nt(
    const float* __restrict__ A, const float* __restrict__ Bw,
    const float* __restrict__ bias, float* __restrict__ C,
    int M, int N, int K, int head_split)
{
    __shared__ float As[KTILE][TILE + 1];  // [k][m]
    __shared__ float Bs[KTILE][TILE + 1];  // [k][n]

    int tid = threadIdx.x;
    int tx = tid & 15;   // n direction (micro col group)
    int ty = tid >> 4;   // m direction (micro row group)
    int m0 = blockIdx.y * TILE;
    int n0 = blockIdx.x * TILE;

    int lk = tid & 15;   // k within tile for loading
    int lm = tid >> 4;   // base row for loading (0..15)

    float c[4][4] = {};

    for (int k0 = 0; k0 < K; k0 += KTILE) {
        #pragma unroll
        for (int i = 0; i < 4; i++) {
            As[lk][lm + 16 * i] = A[(size_t)(m0 + lm + 16 * i) * K + k0 + lk];
            Bs[lk][lm + 16 * i] = Bw[(size_t)(n0 + lm + 16 * i) * K + k0 + lk];
        }
        __syncthreads();
        #pragma unroll
        for (int kk = 0; kk < KTILE; kk++) {
            float a[4], b[4];
            #pragma unroll
            for (int i = 0; i < 4; i++) a[i] = As[kk][ty * 4 + i];
            #pragma unroll
            for (int j = 0; j < 4; j++) b[j] = Bs[kk][tx * 4 + j];
            #pragma unroll
            for (int i = 0; i < 4; i++)
                #pragma unroll
                for (int j = 0; j < 4; j++)
                    c[i][j] += a[i] * b[j];
        }
        __syncthreads();
    }

    #pragma unroll
    for (int i = 0; i < 4; i++) {
        int m = m0 + ty * 4 + i;
        #pragma unroll
        for (int j = 0; j < 4; j++) {
            int n = n0 + tx * 4 + j;
            float v = c[i][j] + bias[n];
            if (head_split) {
                // write [B][H][S][DK]; m = b*S + s ; n = h*DK + dk
                int b = m >> 11;       // / Sn
                int s = m & (Sn - 1);
                int h = n >> 6;        // / DKn
                int dk = n & (DKn - 1);
                C[((size_t)(b * Hn + h) * Sn + s) * DKn + dk] = v;
            } else {
                C[(size_t)m * N + n] = v;
            }
        }
    }
}

// ---------------- Flash attention (fp32, online softmax) ----------------
#define TQ 32
#define TK 64
#define DKP 65   // padded inner dim to kill bank conflicts

__global__ __launch_bounds__(256) void attn(
    const float* __restrict__ Q, const float* __restrict__ Kt,
    const float* __restrict__ Vt, const int* __restrict__ mask,
    float* __restrict__ ctx_out)
{
    __shared__ float Qs[TQ][DKP];
    __shared__ float Ks[TK][DKP];
    __shared__ float Vs[TK][DKP];
    __shared__ float Ps[TQ][TK + 1];
    __shared__ float ctx[TQ][DKP];
    __shared__ float mrow[TQ], lrow[TQ], arow[TQ];

    const int tid = threadIdx.x;
    const int QT_PER = Sn / TQ;                 // 64 query tiles per (b,h)
    int qt  = blockIdx.x % QT_PER;
    int bhh = blockIdx.x / QT_PER;              // b*H + h
    int b   = bhh / Hn;
    int h   = bhh % Hn;

    const float* Qbase = Q  + ((size_t)bhh * Sn + qt * TQ) * DKn;
    const float* Kbase = Kt + (size_t)bhh * Sn * DKn;
    const float* Vbase = Vt + (size_t)bhh * Sn * DKn;
    const int*   mbase = mask + (size_t)b * Sn;

    // load Q tile (pre-scaled by 1/sqrt(DK)), init ctx / m / l
    for (int i = tid; i < TQ * DKn; i += 256) {
        int r = i >> 6, c = i & 63;
        Qs[r][c]  = Qbase[i] * 0.125f;
        ctx[r][c] = 0.f;
    }
    if (tid < TQ) { mrow[tid] = -1e30f; lrow[tid] = 0.f; }
    __syncthreads();

    const int tq = tid >> 4;   // 0..15 -> q rows 2*tq, 2*tq+1
    const int tk = tid & 15;   // 0..15 -> cols 4*tk .. 4*tk+3

    for (int kt = 0; kt < Sn / TK; kt++) {
        // ---- stage K,V tile (contiguous 16KB each) ----
        const float4* K4 = (const float4*)(Kbase + (size_t)kt * TK * DKn);
        const float4* V4 = (const float4*)(Vbase + (size_t)kt * TK * DKn);
        for (int i = tid; i < TK * DKn / 4; i += 256) {
            float4 kv = K4[i];
            float4 vv = V4[i];
            int r = (i * 4) >> 6, c = (i * 4) & 63;
            Ks[r][c] = kv.x; Ks[r][c + 1] = kv.y; Ks[r][c + 2] = kv.z; Ks[r][c + 3] = kv.w;
            Vs[r][c] = vv.x; Vs[r][c + 1] = vv.y; Vs[r][c + 2] = vv.z; Vs[r][c + 3] = vv.w;
        }
        __syncthreads();

        // ---- scores: 2x4 micro-tile per thread ----
        float s[2][4] = {};
        for (int d = 0; d < DKn; d++) {
            float q0 = Qs[2 * tq][d];
            float q1 = Qs[2 * tq + 1][d];
            #pragma unroll
            for (int j = 0; j < 4; j++) {
                float kv = Ks[4 * tk + j][d];
                s[0][j] += q0 * kv;
                s[1][j] += q1 * kv;
            }
        }
        #pragma unroll
        for (int j = 0; j < 4; j++) {
            int kg = kt * TK + 4 * tk + j;
            int mv = mbase[kg];
            float s0 = (mv == 0) ? -1e9f : s[0][j];
            float s1 = (mv == 0) ? -1e9f : s[1][j];
            Ps[2 * tq][4 * tk + j]     = s0;
            Ps[2 * tq + 1][4 * tk + j] = s1;
        }
        __syncthreads();

        // ---- per-row online softmax update (threads 0..31) ----
        if (tid < TQ) {
            float m_old = mrow[tid];
            float mx = m_old;
            for (int j = 0; j < TK; j++) mx = fmaxf(mx, Ps[tid][j]);
            float alpha = __expf(m_old - mx);
            float sum = 0.f;
            for (int j = 0; j < TK; j++) {
                float p = __expf(Ps[tid][j] - mx);
                Ps[tid][j] = p;
                sum += p;
            }
            mrow[tid] = mx;
            lrow[tid] = lrow[tid] * alpha + sum;
            arow[tid] = alpha;
        }
        __syncthreads();

        // ---- ctx update: ctx = ctx*alpha + P @ V, 2x4 micro-tile ----
        float acc[2][4] = {};
        for (int kj = 0; kj < TK; kj++) {
            float p0 = Ps[2 * tq][kj];
            float p1 = Ps[2 * tq + 1][kj];
            #pragma unroll
            for (int j = 0; j < 4; j++) {
                float vv = Vs[kj][4 * tk + j];
                acc[0][j] += p0 * vv;
                acc[1][j] += p1 * vv;
            }
        }
        float a0 = arow[2 * tq];
        float a1 = arow[2 * tq + 1];
        #pragma unroll
        for (int j = 0; j < 4; j++) {
            ctx[2 * tq][4 * tk + j]     = ctx[2 * tq][4 * tk + j] * a0 + acc[0][j];
            ctx[2 * tq + 1][4 * tk + j] = ctx[2 * tq + 1][4 * tk + j] * a1 + acc[1][j];
        }
        __syncthreads();
    }

    // ---- epilogue: normalize by l, write ctx to [B][S][D] (d = h*64 + dk) ----
    for (int i = tid; i < TQ * DKn; i += 256) {
        int r = i >> 6, c = i & 63;
        float inv = 1.f / lrow[r];
        ctx_out[((size_t)(b * Sn + qt * TQ + r)) * Dn + h * DKn + c] = ctx[r][c] * inv;
    }
}

// ---------------- launch ----------------
extern "C" void kernel_launch(void* const* d_in, const int* in_sizes, int n_in,
                              void* d_out, int out_size, void* d_ws, size_t ws_size,
                              hipStream_t stream) {
    const float* x    = (const float*)d_in[0];
    const int*   mask = (const int*)d_in[1];
    const float* Wq   = (const float*)d_in[2];
    const float* bq   = (const float*)d_in[3];
    const float* Wk   = (const float*)d_in[4];
    const float* bk   = (const float*)d_in[5];
    const float* Wv   = (const float*)d_in[6];
    const float* bv   = (const float*)d_in[7];
    const float* Wo   = (const float*)d_in[8];
    const float* bo   = (const float*)d_in[9];
    float* out = (float*)d_out;

    char* ws = (char*)d_ws;
    const size_t QKV_BYTES = (size_t)Bn * Sn * Dn * sizeof(float);  // 16 MB
    float* Qb  = (float*)(ws);
    float* Kb  = (float*)(ws + QKV_BYTES);
    float* Vb  = (float*)(ws + 2 * QKV_BYTES);
    float* CTX = (float*)(ws + 3 * QKV_BYTES);

    const int M = Bn * Sn;   // 4096
    const int N = Dn;        // 1024
    const int K = Dn;        // 1024

    dim3 gemm_grid(N / TILE, M / TILE);   // (16, 64)
    dim3 gemm_block(256);

    // Q, K, V projections (head-split output layout)
    gemm_nt<<<gemm_grid, gemm_block, 0, stream>>>(x, Wq, bq, Qb, M, N, K, 1);
    gemm_nt<<<gemm_grid, gemm_block, 0, stream>>>(x, Wk, bk, Kb, M, N, K, 1);
    gemm_nt<<<gemm_grid, gemm_block, 0, stream>>>(x, Wv, bv, Vb, M, N, K, 1);

    // attention
    dim3 attn_grid(Bn * Hn * (Sn / TQ));  // 2048
    attn<<<attn_grid, 256, 0, stream>>>(Qb, Kb, Vb, mask, CTX);

    // output projection
    gemm_nt<<<gemm_grid, gemm_block, 0, stream>>>(CTX, Wo, bo, out, M, N, K, 0);
}

// Round 2
// 897.125 us; speedup vs baseline: 2.2576x; 2.2576x over previous
//
#include <hip/hip_runtime.h>
#include <hip/hip_bf16.h>
#include <math.h>

// Problem constants
#define Bn 2
#define Sn 2048
#define Dn 1024
#define Hn 16
#define DKn 64

__device__ __forceinline__ short f2bf(float f) {
    union { float f; unsigned u; } v; v.f = f;
    unsigned r = v.u + 0x7FFF + ((v.u >> 16) & 1);   // RNE
    return (short)(r >> 16);
}

// ---------------- GEMM: C[M][N] = A[M][K] * B[N][K] + bias[N] ----------------
// mode 0: fp32 row-major C
// mode 1: bf16 head-split [B][H][S][DK], value scaled by `scale`
// mode 2: bf16 head-split TRANSPOSED [B][H][DK][S]
#define TILE 64
#define KTILE 16

__global__ __launch_bounds__(256) void gemm_nt(
    const float* __restrict__ A, const float* __restrict__ Bw,
    const float* __restrict__ bias, float* __restrict__ Cf,
    short* __restrict__ Cb,
    int M, int N, int K, int mode, float scale)
{
    __shared__ float As[KTILE][TILE + 1];  // [k][m]
    __shared__ float Bs[KTILE][TILE + 1];  // [k][n]

    int tid = threadIdx.x;
    int tx = tid & 15;   // n direction
    int ty = tid >> 4;   // m direction
    int m0 = blockIdx.y * TILE;
    int n0 = blockIdx.x * TILE;

    int lk = tid & 15;
    int lm = tid >> 4;

    float c[4][4] = {};

    for (int k0 = 0; k0 < K; k0 += KTILE) {
        #pragma unroll
        for (int i = 0; i < 4; i++) {
            As[lk][lm + 16 * i] = A[(size_t)(m0 + lm + 16 * i) * K + k0 + lk];
            Bs[lk][lm + 16 * i] = Bw[(size_t)(n0 + lm + 16 * i) * K + k0 + lk];
        }
        __syncthreads();
        #pragma unroll
        for (int kk = 0; kk < KTILE; kk++) {
            float a[4], b[4];
            #pragma unroll
            for (int i = 0; i < 4; i++) a[i] = As[kk][ty * 4 + i];
            #pragma unroll
            for (int j = 0; j < 4; j++) b[j] = Bs[kk][tx * 4 + j];
            #pragma unroll
            for (int i = 0; i < 4; i++)
                #pragma unroll
                for (int j = 0; j < 4; j++)
                    c[i][j] += a[i] * b[j];
        }
        __syncthreads();
    }

    #pragma unroll
    for (int i = 0; i < 4; i++) {
        int m = m0 + ty * 4 + i;
        #pragma unroll
        for (int j = 0; j < 4; j++) {
            int n = n0 + tx * 4 + j;
            float v = c[i][j] + bias[n];
            if (mode == 0) {
                Cf[(size_t)m * N + n] = v;
            } else {
                int b  = m >> 11;          // / Sn
                int s  = m & (Sn - 1);
                int h  = n >> 6;           // / DKn
                int dk = n & (DKn - 1);
                if (mode == 1) {
                    Cb[((size_t)(b * Hn + h) * Sn + s) * DKn + dk] = f2bf(v * scale);
                } else {
                    Cb[((size_t)(b * Hn + h) * DKn + dk) * Sn + s] = f2bf(v);
                }
            }
        }
    }
}

// ---------------- Flash attention, bf16 MFMA ----------------
// block = 256 threads = 4 waves; block handles 64 q-rows of one (b,h);
// wave w handles q-rows [qt*64 + w*16, +16). K iterated in 64-wide chunks.
using frag = __attribute__((ext_vector_type(8))) short;   // 8 bf16
using f4   = __attribute__((ext_vector_type(4))) float;

#define LDK 72   // padded LDS row stride (bf16 units): 144B, breaks bank conflicts

__global__ __launch_bounds__(256) void attn_mfma(
    const short* __restrict__ Qb, const short* __restrict__ Kb,
    const short* __restrict__ Vtb, const int* __restrict__ mask,
    float* __restrict__ ctx_out)
{
    __shared__ short Ks[64 * LDK];        // [k-row][d]
    __shared__ short Vs[64 * LDK];        // [d][k]   (V transposed)
    __shared__ short Ps[4][16 * LDK];     // per-wave P tile [q][k]
    __shared__ int   msk[64];

    const int tid  = threadIdx.x;
    const int wave = tid >> 6;
    const int lane = tid & 63;
    const int quad = lane >> 4;
    const int l16  = lane & 15;

    const int qt  = blockIdx.x & 31;      // Sn/64 = 32 q-tiles
    const int bhh = blockIdx.x >> 5;      // b*H + h
    const int b   = bhh >> 4;
    const int h   = bhh & 15;

    // Q fragments in registers (rows qt*64 + wave*16 + l16), Q pre-scaled by 0.125
    const int qrow = qt * 64 + wave * 16 + l16;
    const short* qptr = Qb + ((size_t)bhh * Sn + qrow) * DKn + quad * 8;
    const frag qf0 = *(const frag*)(qptr);
    const frag qf1 = *(const frag*)(qptr + 32);

    f4 ctx[4];
    #pragma unroll
    for (int dt = 0; dt < 4; dt++) { ctx[dt][0] = 0.f; ctx[dt][1] = 0.f; ctx[dt][2] = 0.f; ctx[dt][3] = 0.f; }
    float m_r[4], l_r[4];
    #pragma unroll
    for (int r = 0; r < 4; r++) { m_r[r] = -1e30f; l_r[r] = 0.f; }

    const short* Kg = Kb  + (size_t)bhh * Sn * DKn;
    const short* Vg = Vtb + (size_t)bhh * DKn * Sn;
    const int*   mg = mask + (size_t)b * Sn;

    for (int kt = 0; kt < Sn / 64; kt++) {
        __syncthreads();
        // stage K chunk: 64 rows x 64 bf16 (contiguous 8KB)
        {
            const uint4* src = (const uint4*)(Kg + (size_t)kt * 64 * DKn);
            #pragma unroll
            for (int c = tid; c < 512; c += 256) {
                int row = c >> 3, col = (c & 7) * 8;
                *(uint4*)&Ks[row * LDK + col] = src[c];
            }
            // stage Vt chunk: 64 d-rows, 64 bf16 slice each (stride Sn)
            #pragma unroll
            for (int c = tid; c < 512; c += 256) {
                int d = c >> 3, kc = (c & 7) * 8;
                *(uint4*)&Vs[d * LDK + kc] =
                    *(const uint4*)(Vg + (size_t)d * Sn + kt * 64 + kc);
            }
            if (tid < 64) msk[tid] = mg[kt * 64 + tid];
        }
        __syncthreads();

        // ---- QK^T: four 16x16 col-subtiles, 2 MFMAs each (d=0..31, 32..63)
        f4 s[4];
        #pragma unroll
        for (int t = 0; t < 4; t++) {
            frag k0 = *(const frag*)&Ks[(t * 16 + l16) * LDK + quad * 8];
            frag k1 = *(const frag*)&Ks[(t * 16 + l16) * LDK + quad * 8 + 32];
            f4 acc; acc[0] = 0.f; acc[1] = 0.f; acc[2] = 0.f; acc[3] = 0.f;
            acc = __builtin_amdgcn_mfma_f32_16x16x32_bf16(qf0, k0, acc, 0, 0, 0);
            acc = __builtin_amdgcn_mfma_f32_16x16x32_bf16(qf1, k1, acc, 0, 0, 0);
            if (msk[t * 16 + l16] == 0) {
                acc[0] = -1e9f; acc[1] = -1e9f; acc[2] = -1e9f; acc[3] = -1e9f;
            }
            s[t] = acc;
        }

        // ---- online softmax per row r (row = quad*4 + r, cols across 16 lanes)
        float alpha[4];
        #pragma unroll
        for (int r = 0; r < 4; r++) {
            float mx = fmaxf(fmaxf(s[0][r], s[1][r]), fmaxf(s[2][r], s[3][r]));
            #pragma unroll
            for (int off = 1; off < 16; off <<= 1)
                mx = fmaxf(mx, __shfl_xor(mx, off, 64));
            float mnew = fmaxf(m_r[r], mx);
            alpha[r] = __expf(m_r[r] - mnew);
            m_r[r] = mnew;
            float sum = 0.f;
            #pragma unroll
            for (int t = 0; t < 4; t++) {
                float p = __expf(s[t][r] - mnew);
                s[t][r] = p;
                sum += p;
            }
            #pragma unroll
            for (int off = 1; off < 16; off <<= 1)
                sum += __shfl_xor(sum, off, 64);
            l_r[r] = l_r[r] * alpha[r] + sum;
        }

        // ---- P (C-layout fp32) -> LDS bf16 [q][k], then read back in A-layout
        #pragma unroll
        for (int t = 0; t < 4; t++)
            #pragma unroll
            for (int r = 0; r < 4; r++)
                Ps[wave][(quad * 4 + r) * LDK + t * 16 + l16] = f2bf(s[t][r]);

        // rescale ctx by alpha
        #pragma unroll
        for (int dt = 0; dt < 4; dt++)
            #pragma unroll
            for (int r = 0; r < 4; r++)
                ctx[dt][r] *= alpha[r];

        frag p0 = *(const frag*)&Ps[wave][l16 * LDK + quad * 8];
        frag p1 = *(const frag*)&Ps[wave][l16 * LDK + quad * 8 + 32];
        #pragma unroll
        for (int dt = 0; dt < 4; dt++) {
            frag v0 = *(const frag*)&Vs[(dt * 16 + l16) * LDK + quad * 8];
            frag v1 = *(const frag*)&Vs[(dt * 16 + l16) * LDK + quad * 8 + 32];
            ctx[dt] = __builtin_amdgcn_mfma_f32_16x16x32_bf16(p0, v0, ctx[dt], 0, 0, 0);
            ctx[dt] = __builtin_amdgcn_mfma_f32_16x16x32_bf16(p1, v1, ctx[dt], 0, 0, 0);
        }
    }

    // ---- epilogue: normalize, write fp32 ctx to [B][S][D] (d = h*64 + dk)
    #pragma unroll
    for (int r = 0; r < 4; r++) {
        float inv = 1.f / l_r[r];
        int row = qt * 64 + wave * 16 + quad * 4 + r;
        #pragma unroll
        for (int dt = 0; dt < 4; dt++) {
            ctx_out[((size_t)(b * Sn + row)) * Dn + h * DKn + dt * 16 + l16] =
                ctx[dt][r] * inv;
        }
    }
}

// ---------------- launch ----------------
extern "C" void kernel_launch(void* const* d_in, const int* in_sizes, int n_in,
                              void* d_out, int out_size, void* d_ws, size_t ws_size,
                              hipStream_t stream) {
    const float* x    = (const float*)d_in[0];
    const int*   mask = (const int*)d_in[1];
    const float* Wq   = (const float*)d_in[2];
    const float* bq   = (const float*)d_in[3];
    const float* Wk   = (const float*)d_in[4];
    const float* bk   = (const float*)d_in[5];
    const float* Wv   = (const float*)d_in[6];
    const float* bv   = (const float*)d_in[7];
    const float* Wo   = (const float*)d_in[8];
    const float* bo   = (const float*)d_in[9];
    float* out = (float*)d_out;

    char* ws = (char*)d_ws;
    const size_t ELEMS = (size_t)Bn * Sn * Dn;       // 4M
    short* Qb  = (short*)(ws);                        // 8 MB bf16
    short* Kb  = (short*)(ws + 8u * 1024 * 1024);     // 8 MB bf16
    short* Vtb = (short*)(ws + 16u * 1024 * 1024);    // 8 MB bf16 (transposed)
    float* CTX = (float*)(ws + 24u * 1024 * 1024);    // 16 MB fp32
    (void)ELEMS;

    const int M = Bn * Sn;   // 4096
    const int N = Dn;        // 1024
    const int K = Dn;        // 1024

    dim3 gemm_grid(N / TILE, M / TILE);
    dim3 gemm_block(256);

    // projections -> bf16 head-split layouts (Q pre-scaled by 1/sqrt(DK))
    gemm_nt<<<gemm_grid, gemm_block, 0, stream>>>(x, Wq, bq, nullptr, Qb,  M, N, K, 1, 0.125f);
    gemm_nt<<<gemm_grid, gemm_block, 0, stream>>>(x, Wk, bk, nullptr, Kb,  M, N, K, 1, 1.0f);
    gemm_nt<<<gemm_grid, gemm_block, 0, stream>>>(x, Wv, bv, nullptr, Vtb, M, N, K, 2, 1.0f);

    // attention (bf16 MFMA flash)
    dim3 attn_grid(Bn * Hn * (Sn / 64));   // 1024 blocks
    attn_mfma<<<attn_grid, 256, 0, stream>>>(Qb, Kb, Vtb, mask, CTX);

    // output projection (fp32)
    gemm_nt<<<gemm_grid, gemm_block, 0, stream>>>(CTX, Wo, bo, out, nullptr, M, N, K, 0, 1.0f);
}

// Round 3
// 382.307 us; speedup vs baseline: 5.2977x; 2.3466x over previous
//
#include <hip/hip_runtime.h>
#include <hip/hip_bf16.h>
#include <math.h>

// Problem constants
#define Bn 2
#define Sn 2048
#define Dn 1024
#define Hn 16
#define DKn 64

using frag = __attribute__((ext_vector_type(8))) short;   // 8 bf16
using f4   = __attribute__((ext_vector_type(4))) float;

__device__ __forceinline__ short f2bf(float f) {
    union { float f; unsigned u; } v; v.f = f;
    unsigned r = v.u + 0x7FFF + ((v.u >> 16) & 1);   // RNE
    return (short)(r >> 16);
}
__device__ __forceinline__ float bf2f(short h) {
    union { unsigned u; float f; } v;
    v.u = ((unsigned)(unsigned short)h) << 16;
    return v.f;
}

// async global->LDS, 16B per lane; LDS dest = wave-uniform base + lane*16
#define GLOAD(gptr, lptr)                                                     \
    __builtin_amdgcn_global_load_lds(                                         \
        (const __attribute__((address_space(1))) unsigned int*)(const void*)(gptr), \
        (__attribute__((address_space(3))) unsigned int*)(void*)(lptr), 16, 0, 0)

// ---------------- fp32 -> bf16 (hi, lo) split ----------------
__global__ __launch_bounds__(256) void split_f32(
    const float* __restrict__ src, short* __restrict__ hi,
    short* __restrict__ lo, int n)
{
    int i = blockIdx.x * 256 + threadIdx.x;
    if (i < n) {
        float v = src[i];
        short h = f2bf(v);
        hi[i] = h;
        lo[i] = f2bf(v - bf2f(h));
    }
}

// ---------------- bf16x3 split-precision MFMA GEMM ----------------
// C[M][Ntot] = A[M][K] * W[Ntot][K]^T + bias, via 3 passes:
//   Ahi*Whi + Alo*Whi + Ahi*Wlo   (error ~2^-18 relative: fp32-grade)
// 128x128 tile, BK=32, 256 threads = 4 waves in 2x2, 64x64 per wave.
// mode 0: epilogue -> bf16 head-split Q (x0.125) / K / V-transposed, by widx
// mode 1: epilogue -> fp32 row-major outf
#define BM 128
#define BN 128
#define BK 32

__global__ __launch_bounds__(256) void gemm_mfma(
    const short* __restrict__ Ahi, const short* __restrict__ Alo,
    const short* __restrict__ W0h, const short* __restrict__ W0l, const float* __restrict__ b0,
    const short* __restrict__ W1h, const short* __restrict__ W1l, const float* __restrict__ b1,
    const short* __restrict__ W2h, const short* __restrict__ W2l, const float* __restrict__ b2,
    short* __restrict__ Qb, short* __restrict__ Kb, short* __restrict__ Vtb,
    float* __restrict__ outf, int mode)
{
    __shared__ __align__(16) short As[BM * BK];   // packed [row][k], 8KB
    __shared__ __align__(16) short Bs[BN * BK];   // packed [row][k], 8KB

    const int tid  = threadIdx.x;
    const int wave = tid >> 6;
    const int lane = tid & 63;
    const int quad = lane >> 4;
    const int l16  = lane & 15;
    const int wm   = wave >> 1;
    const int wn   = wave & 1;

    const int m0  = blockIdx.y * BM;
    const int n0  = blockIdx.x * BN;
    const int widx = n0 >> 10;        // which weight (fused QKV: 0..2)
    const int nl0  = n0 & 1023;       // n within that weight

    const short* Wh   = widx == 0 ? W0h : (widx == 1 ? W1h : W2h);
    const short* Wl   = widx == 0 ? W0l : (widx == 1 ? W1l : W2l);
    const float* bias = widx == 0 ? b0  : (widx == 1 ? b1  : b2);

    f4 acc[4][4];
    #pragma unroll
    for (int i = 0; i < 4; i++)
        #pragma unroll
        for (int j = 0; j < 4; j++) {
            acc[i][j][0] = 0.f; acc[i][j][1] = 0.f;
            acc[i][j][2] = 0.f; acc[i][j][3] = 0.f;
        }

    const int K = Dn;                  // 1024 (row stride of A and W)
    // staging: slot s (0..511) -> row s>>2, k-chunk (s&3)*8; 2 iters of 256
    const int r0  = tid >> 2,        kc0 = (tid & 3) * 8;
    const int r1  = (tid + 256) >> 2, kc1 = (tid & 3) * 8;

    #pragma unroll 1
    for (int part = 0; part < 3; part++) {
        const short* Ap = (part == 1) ? Alo : Ahi;
        const short* Bp = (part == 2) ? Wl  : Wh;
        const short* Ar0 = Ap + (size_t)(m0 + r0) * K + kc0;
        const short* Ar1 = Ap + (size_t)(m0 + r1) * K + kc1;
        const short* Br0 = Bp + (size_t)(nl0 + r0) * K + kc0;
        const short* Br1 = Bp + (size_t)(nl0 + r1) * K + kc1;

        for (int k0 = 0; k0 < K; k0 += BK) {
            __syncthreads();
            GLOAD(Ar0 + k0, &As[(wave * 64) * 8]);
            GLOAD(Ar1 + k0, &As[(256 + wave * 64) * 8]);
            GLOAD(Br0 + k0, &Bs[(wave * 64) * 8]);
            GLOAD(Br1 + k0, &Bs[(256 + wave * 64) * 8]);
            __syncthreads();

            frag a[4], b[4];
            #pragma unroll
            for (int mi = 0; mi < 4; mi++)
                a[mi] = *(const frag*)&As[(wm * 64 + mi * 16 + l16) * BK + quad * 8];
            #pragma unroll
            for (int ni = 0; ni < 4; ni++)
                b[ni] = *(const frag*)&Bs[(wn * 64 + ni * 16 + l16) * BK + quad * 8];
            #pragma unroll
            for (int mi = 0; mi < 4; mi++)
                #pragma unroll
                for (int ni = 0; ni < 4; ni++)
                    acc[mi][ni] = __builtin_amdgcn_mfma_f32_16x16x32_bf16(
                        a[mi], b[ni], acc[mi][ni], 0, 0, 0);
        }
    }

    // epilogue: C[m][n], m = m0+wm*64+mi*16+quad*4+r, n = nl0+wn*64+ni*16+l16
    #pragma unroll
    for (int mi = 0; mi < 4; mi++) {
        #pragma unroll
        for (int ni = 0; ni < 4; ni++) {
            int nl = nl0 + wn * 64 + ni * 16 + l16;
            float bv = bias[nl];
            #pragma unroll
            for (int r = 0; r < 4; r++) {
                int m = m0 + wm * 64 + mi * 16 + quad * 4 + r;
                float v = acc[mi][ni][r] + bv;
                if (mode == 0) {
                    int b  = m >> 11, s = m & (Sn - 1);
                    int h  = nl >> 6, dk = nl & 63;
                    if (widx == 0)
                        Qb[((size_t)(b * Hn + h) * Sn + s) * DKn + dk] = f2bf(v * 0.125f);
                    else if (widx == 1)
                        Kb[((size_t)(b * Hn + h) * Sn + s) * DKn + dk] = f2bf(v);
                    else
                        Vtb[((size_t)(b * Hn + h) * DKn + dk) * Sn + s] = f2bf(v);
                } else {
                    outf[(size_t)m * Dn + nl] = v;
                }
            }
        }
    }
}

// ---------------- Flash attention, bf16 MFMA ----------------
#define LDK 72

__global__ __launch_bounds__(256) void attn_mfma(
    const short* __restrict__ Qb, const short* __restrict__ Kb,
    const short* __restrict__ Vtb, const int* __restrict__ mask,
    short* __restrict__ ctx_hi, short* __restrict__ ctx_lo)
{
    __shared__ short Ks[64 * LDK];
    __shared__ short Vs[64 * LDK];
    __shared__ short Ps[4][16 * LDK];
    __shared__ int   msk[64];

    const int tid  = threadIdx.x;
    const int wave = tid >> 6;
    const int lane = tid & 63;
    const int quad = lane >> 4;
    const int l16  = lane & 15;

    const int qt  = blockIdx.x & 31;
    const int bhh = blockIdx.x >> 5;
    const int b   = bhh >> 4;
    const int h   = bhh & 15;

    const int qrow = qt * 64 + wave * 16 + l16;
    const short* qptr = Qb + ((size_t)bhh * Sn + qrow) * DKn + quad * 8;
    const frag qf0 = *(const frag*)(qptr);
    const frag qf1 = *(const frag*)(qptr + 32);

    f4 ctx[4];
    #pragma unroll
    for (int dt = 0; dt < 4; dt++) { ctx[dt][0] = 0.f; ctx[dt][1] = 0.f; ctx[dt][2] = 0.f; ctx[dt][3] = 0.f; }
    float m_r[4], l_r[4];
    #pragma unroll
    for (int r = 0; r < 4; r++) { m_r[r] = -1e30f; l_r[r] = 0.f; }

    const short* Kg = Kb  + (size_t)bhh * Sn * DKn;
    const short* Vg = Vtb + (size_t)bhh * DKn * Sn;
    const int*   mg = mask + (size_t)b * Sn;

    for (int kt = 0; kt < Sn / 64; kt++) {
        __syncthreads();
        {
            const uint4* src = (const uint4*)(Kg + (size_t)kt * 64 * DKn);
            #pragma unroll
            for (int c = tid; c < 512; c += 256) {
                int row = c >> 3, col = (c & 7) * 8;
                *(uint4*)&Ks[row * LDK + col] = src[c];
            }
            #pragma unroll
            for (int c = tid; c < 512; c += 256) {
                int d = c >> 3, kc = (c & 7) * 8;
                *(uint4*)&Vs[d * LDK + kc] =
                    *(const uint4*)(Vg + (size_t)d * Sn + kt * 64 + kc);
            }
            if (tid < 64) msk[tid] = mg[kt * 64 + tid];
        }
        __syncthreads();

        f4 s[4];
        #pragma unroll
        for (int t = 0; t < 4; t++) {
            frag k0 = *(const frag*)&Ks[(t * 16 + l16) * LDK + quad * 8];
            frag k1 = *(const frag*)&Ks[(t * 16 + l16) * LDK + quad * 8 + 32];
            f4 a; a[0] = 0.f; a[1] = 0.f; a[2] = 0.f; a[3] = 0.f;
            a = __builtin_amdgcn_mfma_f32_16x16x32_bf16(qf0, k0, a, 0, 0, 0);
            a = __builtin_amdgcn_mfma_f32_16x16x32_bf16(qf1, k1, a, 0, 0, 0);
            if (msk[t * 16 + l16] == 0) { a[0] = -1e9f; a[1] = -1e9f; a[2] = -1e9f; a[3] = -1e9f; }
            s[t] = a;
        }

        float alpha[4];
        #pragma unroll
        for (int r = 0; r < 4; r++) {
            float mx = fmaxf(fmaxf(s[0][r], s[1][r]), fmaxf(s[2][r], s[3][r]));
            #pragma unroll
            for (int off = 1; off < 16; off <<= 1)
                mx = fmaxf(mx, __shfl_xor(mx, off, 64));
            float mnew = fmaxf(m_r[r], mx);
            alpha[r] = __expf(m_r[r] - mnew);
            m_r[r] = mnew;
            float sum = 0.f;
            #pragma unroll
            for (int t = 0; t < 4; t++) {
                float p = __expf(s[t][r] - mnew);
                s[t][r] = p;
                sum += p;
            }
            #pragma unroll
            for (int off = 1; off < 16; off <<= 1)
                sum += __shfl_xor(sum, off, 64);
            l_r[r] = l_r[r] * alpha[r] + sum;
        }

        #pragma unroll
        for (int t = 0; t < 4; t++)
            #pragma unroll
            for (int r = 0; r < 4; r++)
                Ps[wave][(quad * 4 + r) * LDK + t * 16 + l16] = f2bf(s[t][r]);

        #pragma unroll
        for (int dt = 0; dt < 4; dt++)
            #pragma unroll
            for (int r = 0; r < 4; r++)
                ctx[dt][r] *= alpha[r];

        frag p0 = *(const frag*)&Ps[wave][l16 * LDK + quad * 8];
        frag p1 = *(const frag*)&Ps[wave][l16 * LDK + quad * 8 + 32];
        #pragma unroll
        for (int dt = 0; dt < 4; dt++) {
            frag v0 = *(const frag*)&Vs[(dt * 16 + l16) * LDK + quad * 8];
            frag v1 = *(const frag*)&Vs[(dt * 16 + l16) * LDK + quad * 8 + 32];
            ctx[dt] = __builtin_amdgcn_mfma_f32_16x16x32_bf16(p0, v0, ctx[dt], 0, 0, 0);
            ctx[dt] = __builtin_amdgcn_mfma_f32_16x16x32_bf16(p1, v1, ctx[dt], 0, 0, 0);
        }
    }

    // epilogue: normalize, split to bf16 hi/lo [B][S][D] (d = h*64 + dk)
    #pragma unroll
    for (int r = 0; r < 4; r++) {
        float inv = 1.f / l_r[r];
        int row = qt * 64 + wave * 16 + quad * 4 + r;
        #pragma unroll
        for (int dt = 0; dt < 4; dt++) {
            float val = ctx[dt][r] * inv;
            size_t idx = ((size_t)(b * Sn + row)) * Dn + h * DKn + dt * 16 + l16;
            short hb = f2bf(val);
            ctx_hi[idx] = hb;
            ctx_lo[idx] = f2bf(val - bf2f(hb));
        }
    }
}

// ---------------- launch ----------------
extern "C" void kernel_launch(void* const* d_in, const int* in_sizes, int n_in,
                              void* d_out, int out_size, void* d_ws, size_t ws_size,
                              hipStream_t stream) {
    const float* x    = (const float*)d_in[0];
    const int*   mask = (const int*)d_in[1];
    const float* Wq   = (const float*)d_in[2];
    const float* bq   = (const float*)d_in[3];
    const float* Wk   = (const float*)d_in[4];
    const float* bk   = (const float*)d_in[5];
    const float* Wv   = (const float*)d_in[6];
    const float* bv   = (const float*)d_in[7];
    const float* Wo   = (const float*)d_in[8];
    const float* bo   = (const float*)d_in[9];
    float* out = (float*)d_out;

    char* ws = (char*)d_ws;
    const size_t MB = 1024u * 1024u;
    short* xhi = (short*)(ws + 0 * MB);    // 8 MB
    short* xlo = (short*)(ws + 8 * MB);    // 8 MB
    short* Wqh = (short*)(ws + 16 * MB);   // 2 MB each below
    short* Wql = (short*)(ws + 18 * MB);
    short* Wkh = (short*)(ws + 20 * MB);
    short* Wkl = (short*)(ws + 22 * MB);
    short* Wvh = (short*)(ws + 24 * MB);
    short* Wvl = (short*)(ws + 26 * MB);
    short* Woh = (short*)(ws + 28 * MB);
    short* Wol = (short*)(ws + 30 * MB);
    short* Qb  = (short*)(ws + 32 * MB);   // 8 MB
    short* Kb  = (short*)(ws + 40 * MB);   // 8 MB
    short* Vtb = (short*)(ws + 48 * MB);   // 8 MB
    short* Chi = (short*)(ws + 56 * MB);   // 8 MB
    short* Clo = (short*)(ws + 64 * MB);   // 8 MB

    const int NX = Bn * Sn * Dn;   // 4M
    const int NW = Dn * Dn;        // 1M

    split_f32<<<NX / 256, 256, 0, stream>>>(x,  xhi, xlo, NX);
    split_f32<<<NW / 256, 256, 0, stream>>>(Wq, Wqh, Wql, NW);
    split_f32<<<NW / 256, 256, 0, stream>>>(Wk, Wkh, Wkl, NW);
    split_f32<<<NW / 256, 256, 0, stream>>>(Wv, Wvh, Wvl, NW);
    split_f32<<<NW / 256, 256, 0, stream>>>(Wo, Woh, Wol, NW);

    // fused QKV projection: N_total = 3072 -> 24 x 32 = 768 blocks
    gemm_mfma<<<dim3(24, 32), 256, 0, stream>>>(
        xhi, xlo,
        Wqh, Wql, bq, Wkh, Wkl, bk, Wvh, Wvl, bv,
        Qb, Kb, Vtb, nullptr, 0);

    // attention
    attn_mfma<<<dim3(Bn * Hn * (Sn / 64)), 256, 0, stream>>>(
        Qb, Kb, Vtb, mask, Chi, Clo);

    // output projection: fp32 out
    gemm_mfma<<<dim3(8, 32), 256, 0, stream>>>(
        Chi, Clo,
        Woh, Wol, bo, Woh, Wol, bo, Woh, Wol, bo,
        nullptr, nullptr, nullptr, out, 1);
}

// Round 4
// 342.433 us; speedup vs baseline: 5.9145x; 1.1164x over previous
//
#include <hip/hip_runtime.h>
#include <hip/hip_bf16.h>
#include <math.h>

// Problem constants
#define Bn 2
#define Sn 2048
#define Dn 1024
#define Hn 16
#define DKn 64

using frag = __attribute__((ext_vector_type(8))) short;   // 8 bf16
using f4   = __attribute__((ext_vector_type(4))) float;

__device__ __forceinline__ short f2bf(float f) {
    union { float f; unsigned u; } v; v.f = f;
    unsigned r = v.u + 0x7FFF + ((v.u >> 16) & 1);   // RNE
    return (short)(r >> 16);
}
__device__ __forceinline__ float bf2f(short h) {
    union { unsigned u; float f; } v;
    v.u = ((unsigned)(unsigned short)h) << 16;
    return v.f;
}

// async global->LDS, 16B per lane; LDS dest = wave-uniform base + lane*16
#define GLOAD(gptr, lptr)                                                     \
    __builtin_amdgcn_global_load_lds(                                         \
        (const __attribute__((address_space(1))) unsigned int*)(const void*)(gptr), \
        (__attribute__((address_space(3))) unsigned int*)(void*)(lptr), 16, 0, 0)

// ---------------- prep: all fp32->bf16 hi/lo splits + bf16 mask row ----------
#define NX (Bn * Sn * Dn)      // 4M
#define NW (Dn * Dn)           // 1M

__global__ __launch_bounds__(256) void prep(
    const float* __restrict__ x,  const float* __restrict__ Wq,
    const float* __restrict__ Wk, const float* __restrict__ Wv,
    const float* __restrict__ Wo, const int* __restrict__ mask,
    short* __restrict__ xhi, short* __restrict__ xlo,
    short* __restrict__ Wqh, short* __restrict__ Wql,
    short* __restrict__ Wkh, short* __restrict__ Wkl,
    short* __restrict__ Wvh, short* __restrict__ Wvl,
    short* __restrict__ Woh, short* __restrict__ Wol,
    short* __restrict__ mfb)
{
    int i = blockIdx.x * 256 + threadIdx.x;
    const float* src; short *hi, *lo; int j;
    if (i < NX)               { src = x;  hi = xhi; lo = xlo; j = i; }
    else if (i < NX + NW)     { src = Wq; hi = Wqh; lo = Wql; j = i - NX; }
    else if (i < NX + 2 * NW) { src = Wk; hi = Wkh; lo = Wkl; j = i - NX - NW; }
    else if (i < NX + 3 * NW) { src = Wv; hi = Wvh; lo = Wvl; j = i - NX - 2 * NW; }
    else if (i < NX + 4 * NW) { src = Wo; hi = Woh; lo = Wol; j = i - NX - 3 * NW; }
    else {
        j = i - NX - 4 * NW;
        if (j < Bn * Sn) mfb[j] = mask[j] ? (short)0x3F80 : (short)0;  // bf16 1/0
        return;
    }
    float v = src[j];
    short h = f2bf(v);
    hi[j] = h;
    lo[j] = f2bf(v - bf2f(h));
}

// ---------------- bf16x3 split-precision MFMA GEMM ----------------
// C = A*W^T + bias via Ahi*Whi + Alo*Whi + Ahi*Wlo.
// mode 0 epilogue: widx 0 -> Q bf16 (x 0.125*log2e), 1 -> K bf16, 2 -> V^T bf16 (masked)
// mode 1 epilogue: fp32 row-major
#define BM 128
#define BN 128
#define BK 32

__global__ __launch_bounds__(256) void gemm_mfma(
    const short* __restrict__ Ahi, const short* __restrict__ Alo,
    const short* __restrict__ W0h, const short* __restrict__ W0l, const float* __restrict__ b0,
    const short* __restrict__ W1h, const short* __restrict__ W1l, const float* __restrict__ b1,
    const short* __restrict__ W2h, const short* __restrict__ W2l, const float* __restrict__ b2,
    const int* __restrict__ mask,
    short* __restrict__ Qb, short* __restrict__ Kb, short* __restrict__ Vtb,
    float* __restrict__ outf, int mode)
{
    __shared__ __align__(16) short As[BM * BK];
    __shared__ __align__(16) short Bs[BN * BK];

    const int tid  = threadIdx.x;
    const int wave = tid >> 6;
    const int lane = tid & 63;
    const int quad = lane >> 4;
    const int l16  = lane & 15;
    const int wm   = wave >> 1;
    const int wn   = wave & 1;

    const int m0  = blockIdx.y * BM;
    const int n0  = blockIdx.x * BN;
    const int widx = n0 >> 10;
    const int nl0  = n0 & 1023;

    const short* Wh   = widx == 0 ? W0h : (widx == 1 ? W1h : W2h);
    const short* Wl   = widx == 0 ? W0l : (widx == 1 ? W1l : W2l);
    const float* bias = widx == 0 ? b0  : (widx == 1 ? b1  : b2);

    f4 acc[4][4];
    #pragma unroll
    for (int i = 0; i < 4; i++)
        #pragma unroll
        for (int j = 0; j < 4; j++) {
            acc[i][j][0] = 0.f; acc[i][j][1] = 0.f;
            acc[i][j][2] = 0.f; acc[i][j][3] = 0.f;
        }

    const int K = Dn;
    const int r0  = tid >> 2,         kc0 = (tid & 3) * 8;
    const int r1  = (tid + 256) >> 2, kc1 = (tid & 3) * 8;

    #pragma unroll 1
    for (int part = 0; part < 3; part++) {
        const short* Ap = (part == 1) ? Alo : Ahi;
        const short* Bp = (part == 2) ? Wl  : Wh;
        const short* Ar0 = Ap + (size_t)(m0 + r0) * K + kc0;
        const short* Ar1 = Ap + (size_t)(m0 + r1) * K + kc1;
        const short* Br0 = Bp + (size_t)(nl0 + r0) * K + kc0;
        const short* Br1 = Bp + (size_t)(nl0 + r1) * K + kc1;

        for (int k0 = 0; k0 < K; k0 += BK) {
            __syncthreads();
            GLOAD(Ar0 + k0, &As[(wave * 64) * 8]);
            GLOAD(Ar1 + k0, &As[(256 + wave * 64) * 8]);
            GLOAD(Br0 + k0, &Bs[(wave * 64) * 8]);
            GLOAD(Br1 + k0, &Bs[(256 + wave * 64) * 8]);
            __syncthreads();

            frag a[4], b[4];
            #pragma unroll
            for (int mi = 0; mi < 4; mi++)
                a[mi] = *(const frag*)&As[(wm * 64 + mi * 16 + l16) * BK + quad * 8];
            #pragma unroll
            for (int ni = 0; ni < 4; ni++)
                b[ni] = *(const frag*)&Bs[(wn * 64 + ni * 16 + l16) * BK + quad * 8];
            #pragma unroll
            for (int mi = 0; mi < 4; mi++)
                #pragma unroll
                for (int ni = 0; ni < 4; ni++)
                    acc[mi][ni] = __builtin_amdgcn_mfma_f32_16x16x32_bf16(
                        a[mi], b[ni], acc[mi][ni], 0, 0, 0);
        }
    }

    // Q scale folds 1/sqrt(DK) and log2(e) so attention can use raw v_exp (2^x)
    const float QSCALE = 0.125f * 1.44269504088896340736f;

    #pragma unroll
    for (int mi = 0; mi < 4; mi++) {
        #pragma unroll
        for (int ni = 0; ni < 4; ni++) {
            int nl = nl0 + wn * 64 + ni * 16 + l16;
            float bv = bias[nl];
            #pragma unroll
            for (int r = 0; r < 4; r++) {
                int m = m0 + wm * 64 + mi * 16 + quad * 4 + r;
                float v = acc[mi][ni][r] + bv;
                if (mode == 0) {
                    int b  = m >> 11, s = m & (Sn - 1);
                    int h  = nl >> 6, dk = nl & 63;
                    if (widx == 0)
                        Qb[((size_t)(b * Hn + h) * Sn + s) * DKn + dk] = f2bf(v * QSCALE);
                    else if (widx == 1)
                        Kb[((size_t)(b * Hn + h) * Sn + s) * DKn + dk] = f2bf(v);
                    else {
                        float mv = (float)mask[b * Sn + s];   // mask applied to V rows
                        Vtb[((size_t)(b * Hn + h) * DKn + dk) * Sn + s] = f2bf(v * mv);
                    }
                } else {
                    outf[(size_t)m * Dn + nl] = v;
                }
            }
        }
    }
}

// ---------------- Flash attention, bf16 MFMA, max-free softmax ----------------
// S^T = mfma(K-frag, Q-frag) -> per lane 4 k-consecutive scores -> exp2 ->
// perm-pack -> ds_write_b64 into Ps[q][k] -> A-frag reads for PV.
// l from 2 extra MFMAs vs broadcast bf16 mask-row (lands in C-frag layout).
#define LDK 72
#define LP  72

__global__ __launch_bounds__(256) void attn_mfma(
    const short* __restrict__ Qb, const short* __restrict__ Kb,
    const short* __restrict__ Vtb, const short* __restrict__ mfb,
    short* __restrict__ ctx_hi, short* __restrict__ ctx_lo)
{
    __shared__ short Ks[64 * LDK];
    __shared__ short Vs[64 * LDK];
    __shared__ short Ps[4][16 * LP];
    __shared__ __align__(16) short mfs[64];

    const int tid  = threadIdx.x;
    const int wave = tid >> 6;
    const int lane = tid & 63;
    const int quad = lane >> 4;
    const int l16  = lane & 15;

    const int qt  = blockIdx.x & 31;
    const int bhh = blockIdx.x >> 5;
    const int b   = bhh >> 4;
    const int h   = bhh & 15;

    const int qrow = qt * 64 + wave * 16 + l16;
    const short* qptr = Qb + ((size_t)bhh * Sn + qrow) * DKn + quad * 8;
    const frag qf0 = *(const frag*)(qptr);
    const frag qf1 = *(const frag*)(qptr + 32);

    f4 ctx[4];
    #pragma unroll
    for (int dt = 0; dt < 4; dt++) { ctx[dt][0] = 0.f; ctx[dt][1] = 0.f; ctx[dt][2] = 0.f; ctx[dt][3] = 0.f; }
    f4 lacc; lacc[0] = 0.f; lacc[1] = 0.f; lacc[2] = 0.f; lacc[3] = 0.f;

    const short* Kg = Kb  + (size_t)bhh * Sn * DKn;
    const short* Vg = Vtb + (size_t)bhh * DKn * Sn;
    const short* mg = mfb + (size_t)b * Sn;

    for (int kt = 0; kt < Sn / 64; kt++) {
        __syncthreads();
        {
            const uint4* src = (const uint4*)(Kg + (size_t)kt * 64 * DKn);
            #pragma unroll
            for (int c = tid; c < 512; c += 256) {
                int row = c >> 3, col = (c & 7) * 8;
                *(uint4*)&Ks[row * LDK + col] = src[c];
            }
            #pragma unroll
            for (int c = tid; c < 512; c += 256) {
                int d = c >> 3, kc = (c & 7) * 8;
                *(uint4*)&Vs[d * LDK + kc] =
                    *(const uint4*)(Vg + (size_t)d * Sn + kt * 64 + kc);
            }
            if (tid < 8)
                *(uint4*)&mfs[tid * 8] = *(const uint4*)(mg + kt * 64 + tid * 8);
        }
        __syncthreads();

        // ---- S^T: rows k, cols q. Per lane: k = 16t + quad*4 + r, q = l16.
        #pragma unroll
        for (int t = 0; t < 4; t++) {
            frag k0 = *(const frag*)&Ks[(t * 16 + l16) * LDK + quad * 8];
            frag k1 = *(const frag*)&Ks[(t * 16 + l16) * LDK + quad * 8 + 32];
            f4 a; a[0] = 0.f; a[1] = 0.f; a[2] = 0.f; a[3] = 0.f;
            a = __builtin_amdgcn_mfma_f32_16x16x32_bf16(k0, qf0, a, 0, 0, 0);
            a = __builtin_amdgcn_mfma_f32_16x16x32_bf16(k1, qf1, a, 0, 0, 0);
            // p = 2^s (log2e folded into Q); pack 4 bf16 (truncate) and store b64
            unsigned u0 = __float_as_uint(exp2f(a[0]));
            unsigned u1 = __float_as_uint(exp2f(a[1]));
            unsigned u2 = __float_as_uint(exp2f(a[2]));
            unsigned u3 = __float_as_uint(exp2f(a[3]));
            uint2 w;
            w.x = __builtin_amdgcn_perm(u1, u0, 0x07060302u);
            w.y = __builtin_amdgcn_perm(u3, u2, 0x07060302u);
            *(uint2*)&Ps[wave][l16 * LP + 16 * t + quad * 4] = w;
        }

        // ---- PV + l accumulation
        frag p0 = *(const frag*)&Ps[wave][l16 * LP + quad * 8];
        frag p1 = *(const frag*)&Ps[wave][l16 * LP + quad * 8 + 32];
        frag m0 = *(const frag*)&mfs[quad * 8];
        frag m1 = *(const frag*)&mfs[quad * 8 + 32];
        lacc = __builtin_amdgcn_mfma_f32_16x16x32_bf16(p0, m0, lacc, 0, 0, 0);
        lacc = __builtin_amdgcn_mfma_f32_16x16x32_bf16(p1, m1, lacc, 0, 0, 0);
        #pragma unroll
        for (int dt = 0; dt < 4; dt++) {
            frag v0 = *(const frag*)&Vs[(dt * 16 + l16) * LDK + quad * 8];
            frag v1 = *(const frag*)&Vs[(dt * 16 + l16) * LDK + quad * 8 + 32];
            ctx[dt] = __builtin_amdgcn_mfma_f32_16x16x32_bf16(p0, v0, ctx[dt], 0, 0, 0);
            ctx[dt] = __builtin_amdgcn_mfma_f32_16x16x32_bf16(p1, v1, ctx[dt], 0, 0, 0);
        }
    }

    // ---- epilogue: rows q = quad*4+r, cols d = l16 (per dt); l in lacc[r]
    #pragma unroll
    for (int r = 0; r < 4; r++) {
        float inv = 1.f / lacc[r];
        int row = qt * 64 + wave * 16 + quad * 4 + r;
        #pragma unroll
        for (int dt = 0; dt < 4; dt++) {
            float val = ctx[dt][r] * inv;
            size_t idx = ((size_t)(b * Sn + row)) * Dn + h * DKn + dt * 16 + l16;
            short hb = f2bf(val);
            ctx_hi[idx] = hb;
            ctx_lo[idx] = f2bf(val - bf2f(hb));
        }
    }
}

// ---------------- launch ----------------
extern "C" void kernel_launch(void* const* d_in, const int* in_sizes, int n_in,
                              void* d_out, int out_size, void* d_ws, size_t ws_size,
                              hipStream_t stream) {
    const float* x    = (const float*)d_in[0];
    const int*   mask = (const int*)d_in[1];
    const float* Wq   = (const float*)d_in[2];
    const float* bq   = (const float*)d_in[3];
    const float* Wk   = (const float*)d_in[4];
    const float* bk   = (const float*)d_in[5];
    const float* Wv   = (const float*)d_in[6];
    const float* bv   = (const float*)d_in[7];
    const float* Wo   = (const float*)d_in[8];
    const float* bo   = (const float*)d_in[9];
    float* out = (float*)d_out;

    char* ws = (char*)d_ws;
    const size_t MB = 1024u * 1024u;
    short* xhi = (short*)(ws + 0 * MB);
    short* xlo = (short*)(ws + 8 * MB);
    short* Wqh = (short*)(ws + 16 * MB);
    short* Wql = (short*)(ws + 18 * MB);
    short* Wkh = (short*)(ws + 20 * MB);
    short* Wkl = (short*)(ws + 22 * MB);
    short* Wvh = (short*)(ws + 24 * MB);
    short* Wvl = (short*)(ws + 26 * MB);
    short* Woh = (short*)(ws + 28 * MB);
    short* Wol = (short*)(ws + 30 * MB);
    short* Qb  = (short*)(ws + 32 * MB);
    short* Kb  = (short*)(ws + 40 * MB);
    short* Vtb = (short*)(ws + 48 * MB);
    short* Chi = (short*)(ws + 56 * MB);
    short* Clo = (short*)(ws + 64 * MB);
    short* mfb = (short*)(ws + 72 * MB);   // bf16 mask row, Bn*Sn

    const int TOT = NX + 4 * NW + Bn * Sn;
    prep<<<(TOT + 255) / 256, 256, 0, stream>>>(
        x, Wq, Wk, Wv, Wo, mask,
        xhi, xlo, Wqh, Wql, Wkh, Wkl, Wvh, Wvl, Woh, Wol, mfb);

    // fused QKV projection: N_total = 3072 -> 24 x 32 blocks
    gemm_mfma<<<dim3(24, 32), 256, 0, stream>>>(
        xhi, xlo,
        Wqh, Wql, bq, Wkh, Wkl, bk, Wvh, Wvl, bv, mask,
        Qb, Kb, Vtb, nullptr, 0);

    // attention
    attn_mfma<<<dim3(Bn * Hn * (Sn / 64)), 256, 0, stream>>>(
        Qb, Kb, Vtb, mfb, Chi, Clo);

    // output projection: fp32 out
    gemm_mfma<<<dim3(8, 32), 256, 0, stream>>>(
        Chi, Clo,
        Woh, Wol, bo, Woh, Wol, bo, Woh, Wol, bo, mask,
        nullptr, nullptr, nullptr, out, 1);
}

// Round 5
// 250.043 us; speedup vs baseline: 8.0999x; 1.3695x over previous
//
#include <hip/hip_runtime.h>
#include <hip/hip_bf16.h>
#include <math.h>

// Problem constants
#define Bn 2
#define Sn 2048
#define Dn 1024
#define Hn 16
#define DKn 64

using fragb  = __attribute__((ext_vector_type(8))) short;      // 8 bf16
using frag16 = __attribute__((ext_vector_type(8))) _Float16;   // 8 fp16
using f4     = __attribute__((ext_vector_type(4))) float;

__device__ __forceinline__ short f2bf(float f) {
    union { float f; unsigned u; } v; v.f = f;
    unsigned r = v.u + 0x7FFF + ((v.u >> 16) & 1);   // RNE
    return (short)(r >> 16);
}
__device__ __forceinline__ float bf2f(short h) {
    union { unsigned u; float f; } v;
    v.u = ((unsigned)(unsigned short)h) << 16;
    return v.f;
}
__device__ __forceinline__ short f2h(float f) {
    _Float16 h = (_Float16)f;                         // RNE
    short s; __builtin_memcpy(&s, &h, 2); return s;
}

// async global->LDS, 16B per lane; LDS dest = wave-uniform base + lane*16
#define GLOAD(gptr, lptr)                                                     \
    __builtin_amdgcn_global_load_lds(                                         \
        (const __attribute__((address_space(1))) unsigned int*)(const void*)(gptr), \
        (__attribute__((address_space(3))) unsigned int*)(void*)(lptr), 16, 0, 0)

// ---------------- prep: fp32 -> fp16 casts + bf16 mask row ----------------
#define NX (Bn * Sn * Dn)      // 4M
#define NW (Dn * Dn)           // 1M

__global__ __launch_bounds__(256) void prep(
    const float* __restrict__ x,  const float* __restrict__ Wq,
    const float* __restrict__ Wk, const float* __restrict__ Wv,
    const float* __restrict__ Wo, const int* __restrict__ mask,
    short* __restrict__ xh,
    short* __restrict__ Wqh, short* __restrict__ Wkh,
    short* __restrict__ Wvh, short* __restrict__ Woh,
    short* __restrict__ mfb)
{
    int i = blockIdx.x * 256 + threadIdx.x;
    const float* src; short* dst; int j;
    if (i < NX)               { src = x;  dst = xh;  j = i; }
    else if (i < NX + NW)     { src = Wq; dst = Wqh; j = i - NX; }
    else if (i < NX + 2 * NW) { src = Wk; dst = Wkh; j = i - NX - NW; }
    else if (i < NX + 3 * NW) { src = Wv; dst = Wvh; j = i - NX - 2 * NW; }
    else if (i < NX + 4 * NW) { src = Wo; dst = Woh; j = i - NX - 3 * NW; }
    else {
        j = i - NX - 4 * NW;
        if (j < Bn * Sn) mfb[j] = mask[j] ? (short)0x3F80 : (short)0;  // bf16 1/0
        return;
    }
    dst[j] = f2h(src[j]);
}

// ---------------- fp16 single-pass MFMA GEMM ----------------
// C[M][Ntot] = A[M][K]*W[Ntot][K]^T + bias (fp32 accumulate in MFMA).
// mode 0 epilogue: widx 0 -> Q bf16 (x 0.125*log2e), 1 -> K bf16, 2 -> V^T bf16 (masked)
// mode 1 epilogue: fp32 row-major
// LDS k-chunk XOR swizzle: chunk slot = quad ^ ((row>>2)&3)  -> 2-way (free) b128 reads
#define BN 128
#define BK 32

template <int BMT>
__global__ __launch_bounds__(256) void gemm_mfma(
    const short* __restrict__ A,
    const short* __restrict__ W0, const float* __restrict__ b0,
    const short* __restrict__ W1, const float* __restrict__ b1,
    const short* __restrict__ W2, const float* __restrict__ b2,
    const int* __restrict__ mask,
    short* __restrict__ Qb, short* __restrict__ Kb, short* __restrict__ Vtb,
    float* __restrict__ outf, int mode)
{
    constexpr int MI = BMT / 32;                    // 16-row frags per wave (m dir)
    __shared__ __align__(16) short As[BMT * BK];
    __shared__ __align__(16) short Bs[BN * BK];

    const int tid  = threadIdx.x;
    const int wave = tid >> 6;
    const int lane = tid & 63;
    const int quad = lane >> 4;
    const int l16  = lane & 15;
    const int wm   = wave >> 1;
    const int wn   = wave & 1;

    const int m0   = blockIdx.y * BMT;
    const int n0   = blockIdx.x * BN;
    const int widx = n0 >> 10;
    const int nl0  = n0 & 1023;

    const short* Wp   = widx == 0 ? W0 : (widx == 1 ? W1 : W2);
    const float* bias = widx == 0 ? b0 : (widx == 1 ? b1 : b2);

    f4 acc[MI][4];
    #pragma unroll
    for (int i = 0; i < MI; i++)
        #pragma unroll
        for (int j = 0; j < 4; j++) {
            acc[i][j][0] = 0.f; acc[i][j][1] = 0.f;
            acc[i][j][2] = 0.f; acc[i][j][3] = 0.f;
        }

    const int K = Dn;
    // staging: lane's slot = tid (+256); row = slot>>2, k-chunk XOR-swizzled
    const int lrow = tid >> 2;
    const int lkc  = ((tid & 3) ^ ((tid >> 4) & 3)) * 8;
    const short* Ar = A  + (size_t)(m0  + lrow) * K + lkc;
    const short* Br = Wp + (size_t)(nl0 + lrow) * K + lkc;

    const int sw = (l16 >> 2) & 3;                  // read-side swizzle
    const int ca = ((quad ^ sw) * 8);

    for (int k0 = 0; k0 < K; k0 += BK) {
        __syncthreads();
        GLOAD(Ar + k0, &As[wave * 512]);
        if constexpr (BMT == 128)
            GLOAD(Ar + (size_t)64 * K + k0, &As[2048 + wave * 512]);
        GLOAD(Br + k0, &Bs[wave * 512]);
        GLOAD(Br + (size_t)64 * K + k0, &Bs[2048 + wave * 512]);
        __syncthreads();

        frag16 a[MI], b[4];
        #pragma unroll
        for (int mi = 0; mi < MI; mi++)
            a[mi] = *(const frag16*)&As[(wm * (BMT / 2) + mi * 16 + l16) * BK + ca];
        #pragma unroll
        for (int ni = 0; ni < 4; ni++)
            b[ni] = *(const frag16*)&Bs[(wn * 64 + ni * 16 + l16) * BK + ca];
        #pragma unroll
        for (int mi = 0; mi < MI; mi++)
            #pragma unroll
            for (int ni = 0; ni < 4; ni++)
                acc[mi][ni] = __builtin_amdgcn_mfma_f32_16x16x32_f16(
                    a[mi], b[ni], acc[mi][ni], 0, 0, 0);
    }

    // Q scale folds 1/sqrt(DK) and log2(e) so attention can use raw 2^x
    const float QSCALE = 0.125f * 1.44269504088896340736f;

    #pragma unroll
    for (int mi = 0; mi < MI; mi++) {
        #pragma unroll
        for (int ni = 0; ni < 4; ni++) {
            int nl = nl0 + wn * 64 + ni * 16 + l16;
            float bv = bias[nl];
            #pragma unroll
            for (int r = 0; r < 4; r++) {
                int m = m0 + wm * (BMT / 2) + mi * 16 + quad * 4 + r;
                float v = acc[mi][ni][r] + bv;
                if (mode == 0) {
                    int b  = m >> 11, s = m & (Sn - 1);
                    int h  = nl >> 6, dk = nl & 63;
                    if (widx == 0)
                        Qb[((size_t)(b * Hn + h) * Sn + s) * DKn + dk] = f2bf(v * QSCALE);
                    else if (widx == 1)
                        Kb[((size_t)(b * Hn + h) * Sn + s) * DKn + dk] = f2bf(v);
                    else {
                        float mv = (float)mask[b * Sn + s];   // mask applied to V rows
                        Vtb[((size_t)(b * Hn + h) * DKn + dk) * Sn + s] = f2bf(v * mv);
                    }
                } else {
                    outf[(size_t)m * Dn + nl] = v;
                }
            }
        }
    }
}

// ---------------- Flash attention, bf16 MFMA, max-free softmax ----------------
#define LDK 72
#define LP  72

__global__ __launch_bounds__(256) void attn_mfma(
    const short* __restrict__ Qb, const short* __restrict__ Kb,
    const short* __restrict__ Vtb, const short* __restrict__ mfb,
    short* __restrict__ ctxh)
{
    __shared__ short Ks[64 * LDK];
    __shared__ short Vs[64 * LDK];
    __shared__ short Ps[4][16 * LP];
    __shared__ __align__(16) short mfs[64];

    const int tid  = threadIdx.x;
    const int wave = tid >> 6;
    const int lane = tid & 63;
    const int quad = lane >> 4;
    const int l16  = lane & 15;

    const int qt  = blockIdx.x & 31;
    const int bhh = blockIdx.x >> 5;
    const int b   = bhh >> 4;
    const int h   = bhh & 15;

    const int qrow = qt * 64 + wave * 16 + l16;
    const short* qptr = Qb + ((size_t)bhh * Sn + qrow) * DKn + quad * 8;
    const fragb qf0 = *(const fragb*)(qptr);
    const fragb qf1 = *(const fragb*)(qptr + 32);

    f4 ctx[4];
    #pragma unroll
    for (int dt = 0; dt < 4; dt++) { ctx[dt][0] = 0.f; ctx[dt][1] = 0.f; ctx[dt][2] = 0.f; ctx[dt][3] = 0.f; }
    f4 lacc; lacc[0] = 0.f; lacc[1] = 0.f; lacc[2] = 0.f; lacc[3] = 0.f;

    const short* Kg = Kb  + (size_t)bhh * Sn * DKn;
    const short* Vg = Vtb + (size_t)bhh * DKn * Sn;
    const short* mg = mfb + (size_t)b * Sn;

    for (int kt = 0; kt < Sn / 64; kt++) {
        __syncthreads();
        {
            const uint4* src = (const uint4*)(Kg + (size_t)kt * 64 * DKn);
            #pragma unroll
            for (int c = tid; c < 512; c += 256) {
                int row = c >> 3, col = (c & 7) * 8;
                *(uint4*)&Ks[row * LDK + col] = src[c];
            }
            #pragma unroll
            for (int c = tid; c < 512; c += 256) {
                int d = c >> 3, kc = (c & 7) * 8;
                *(uint4*)&Vs[d * LDK + kc] =
                    *(const uint4*)(Vg + (size_t)d * Sn + kt * 64 + kc);
            }
            if (tid < 8)
                *(uint4*)&mfs[tid * 8] = *(const uint4*)(mg + kt * 64 + tid * 8);
        }
        __syncthreads();

        // ---- S^T: rows k, cols q. Per lane: k = 16t + quad*4 + r, q = l16.
        #pragma unroll
        for (int t = 0; t < 4; t++) {
            fragb k0 = *(const fragb*)&Ks[(t * 16 + l16) * LDK + quad * 8];
            fragb k1 = *(const fragb*)&Ks[(t * 16 + l16) * LDK + quad * 8 + 32];
            f4 a; a[0] = 0.f; a[1] = 0.f; a[2] = 0.f; a[3] = 0.f;
            a = __builtin_amdgcn_mfma_f32_16x16x32_bf16(k0, qf0, a, 0, 0, 0);
            a = __builtin_amdgcn_mfma_f32_16x16x32_bf16(k1, qf1, a, 0, 0, 0);
            unsigned u0 = __float_as_uint(exp2f(a[0]));
            unsigned u1 = __float_as_uint(exp2f(a[1]));
            unsigned u2 = __float_as_uint(exp2f(a[2]));
            unsigned u3 = __float_as_uint(exp2f(a[3]));
            uint2 w;
            w.x = __builtin_amdgcn_perm(u1, u0, 0x07060302u);
            w.y = __builtin_amdgcn_perm(u3, u2, 0x07060302u);
            *(uint2*)&Ps[wave][l16 * LP + 16 * t + quad * 4] = w;
        }

        // ---- PV + l accumulation
        fragb p0 = *(const fragb*)&Ps[wave][l16 * LP + quad * 8];
        fragb p1 = *(const fragb*)&Ps[wave][l16 * LP + quad * 8 + 32];
        fragb m0 = *(const fragb*)&mfs[quad * 8];
        fragb m1 = *(const fragb*)&mfs[quad * 8 + 32];
        lacc = __builtin_amdgcn_mfma_f32_16x16x32_bf16(p0, m0, lacc, 0, 0, 0);
        lacc = __builtin_amdgcn_mfma_f32_16x16x32_bf16(p1, m1, lacc, 0, 0, 0);
        #pragma unroll
        for (int dt = 0; dt < 4; dt++) {
            fragb v0 = *(const fragb*)&Vs[(dt * 16 + l16) * LDK + quad * 8];
            fragb v1 = *(const fragb*)&Vs[(dt * 16 + l16) * LDK + quad * 8 + 32];
            ctx[dt] = __builtin_amdgcn_mfma_f32_16x16x32_bf16(p0, v0, ctx[dt], 0, 0, 0);
            ctx[dt] = __builtin_amdgcn_mfma_f32_16x16x32_bf16(p1, v1, ctx[dt], 0, 0, 0);
        }
    }

    // ---- epilogue: rows q = quad*4+r, cols d = l16 (per dt); l in lacc[r]
    #pragma unroll
    for (int r = 0; r < 4; r++) {
        float inv = 1.f / lacc[r];
        int row = qt * 64 + wave * 16 + quad * 4 + r;
        #pragma unroll
        for (int dt = 0; dt < 4; dt++) {
            float val = ctx[dt][r] * inv;
            size_t idx = ((size_t)(b * Sn + row)) * Dn + h * DKn + dt * 16 + l16;
            ctxh[idx] = f2h(val);
        }
    }
}

// ---------------- launch ----------------
extern "C" void kernel_launch(void* const* d_in, const int* in_sizes, int n_in,
                              void* d_out, int out_size, void* d_ws, size_t ws_size,
                              hipStream_t stream) {
    const float* x    = (const float*)d_in[0];
    const int*   mask = (const int*)d_in[1];
    const float* Wq   = (const float*)d_in[2];
    const float* bq   = (const float*)d_in[3];
    const float* Wk   = (const float*)d_in[4];
    const float* bk   = (const float*)d_in[5];
    const float* Wv   = (const float*)d_in[6];
    const float* bv   = (const float*)d_in[7];
    const float* Wo   = (const float*)d_in[8];
    const float* bo   = (const float*)d_in[9];
    float* out = (float*)d_out;

    char* ws = (char*)d_ws;
    const size_t MB = 1024u * 1024u;
    short* xh  = (short*)(ws + 0 * MB);    // 8 MB fp16
    short* Wqh = (short*)(ws + 8 * MB);    // 2 MB each
    short* Wkh = (short*)(ws + 10 * MB);
    short* Wvh = (short*)(ws + 12 * MB);
    short* Woh = (short*)(ws + 14 * MB);
    short* Qb  = (short*)(ws + 16 * MB);   // 8 MB bf16
    short* Kb  = (short*)(ws + 24 * MB);   // 8 MB bf16
    short* Vtb = (short*)(ws + 32 * MB);   // 8 MB bf16 (transposed, masked)
    short* Ch  = (short*)(ws + 40 * MB);   // 8 MB fp16 ctx
    short* mfb = (short*)(ws + 48 * MB);   // bf16 mask row

    const int TOT = NX + 4 * NW + Bn * Sn;
    prep<<<(TOT + 255) / 256, 256, 0, stream>>>(
        x, Wq, Wk, Wv, Wo, mask, xh, Wqh, Wkh, Wvh, Woh, mfb);

    // fused QKV projection: N_total = 3072 -> 24 x 32 blocks (BM=128)
    gemm_mfma<128><<<dim3(24, 32), 256, 0, stream>>>(
        xh, Wqh, bq, Wkh, bk, Wvh, bv, mask,
        Qb, Kb, Vtb, nullptr, 0);

    // attention
    attn_mfma<<<dim3(Bn * Hn * (Sn / 64)), 256, 0, stream>>>(
        Qb, Kb, Vtb, mfb, Ch);

    // output projection: fp32 out (BM=64 -> 512 blocks, 2/CU)
    gemm_mfma<64><<<dim3(8, 64), 256, 0, stream>>>(
        Ch, Woh, bo, Woh, bo, Woh, bo, mask,
        nullptr, nullptr, nullptr, out, 1);
}

// Round 6
// 232.645 us; speedup vs baseline: 8.7057x; 1.0748x over previous
//
#include <hip/hip_runtime.h>
#include <hip/hip_bf16.h>
#include <math.h>

// Problem constants
#define Bn 2
#define Sn 2048
#define Dn 1024
#define Hn 16
#define DKn 64

using fragb  = __attribute__((ext_vector_type(8))) short;      // 8 bf16
using frag16 = __attribute__((ext_vector_type(8))) _Float16;   // 8 fp16
using f4     = __attribute__((ext_vector_type(4))) float;

__device__ __forceinline__ short f2bf(float f) {
    union { float f; unsigned u; } v; v.f = f;
    unsigned r = v.u + 0x7FFF + ((v.u >> 16) & 1);   // RNE
    return (short)(r >> 16);
}
__device__ __forceinline__ float bf2f(short h) {
    union { unsigned u; float f; } v;
    v.u = ((unsigned)(unsigned short)h) << 16;
    return v.f;
}
__device__ __forceinline__ short f2h(float f) {
    _Float16 h = (_Float16)f;                         // RNE
    short s; __builtin_memcpy(&s, &h, 2); return s;
}

// async global->LDS, 16B per lane; LDS dest = wave-uniform base + lane*16
#define GLOAD(gptr, lptr)                                                     \
    __builtin_amdgcn_global_load_lds(                                         \
        (const __attribute__((address_space(1))) unsigned int*)(const void*)(gptr), \
        (__attribute__((address_space(3))) unsigned int*)(void*)(lptr), 16, 0, 0)

// ---------------- prep: fp32 -> fp16 casts + bf16 mask row ----------------
#define NX (Bn * Sn * Dn)      // 4M
#define NW (Dn * Dn)           // 1M

__global__ __launch_bounds__(256) void prep(
    const float* __restrict__ x,  const float* __restrict__ Wq,
    const float* __restrict__ Wk, const float* __restrict__ Wv,
    const float* __restrict__ Wo, const int* __restrict__ mask,
    short* __restrict__ xh,
    short* __restrict__ Wqh, short* __restrict__ Wkh,
    short* __restrict__ Wvh, short* __restrict__ Woh,
    short* __restrict__ mfb)
{
    int i = blockIdx.x * 256 + threadIdx.x;
    const float* src; short* dst; int j;
    if (i < NX)               { src = x;  dst = xh;  j = i; }
    else if (i < NX + NW)     { src = Wq; dst = Wqh; j = i - NX; }
    else if (i < NX + 2 * NW) { src = Wk; dst = Wkh; j = i - NX - NW; }
    else if (i < NX + 3 * NW) { src = Wv; dst = Wvh; j = i - NX - 2 * NW; }
    else if (i < NX + 4 * NW) { src = Wo; dst = Woh; j = i - NX - 3 * NW; }
    else {
        j = i - NX - 4 * NW;
        if (j < Bn * Sn) mfb[j] = mask[j] ? (short)0x3F80 : (short)0;  // bf16 1/0
        return;
    }
    dst[j] = f2h(src[j]);
}

// ---------------- fp16 single-pass MFMA GEMM ----------------
// C[M][Ntot] = A[M][K]*W[Ntot][K]^T + bias (fp32 accumulate in MFMA).
// mode 0 epilogue: widx 0 -> Q bf16 (x 0.125*log2e), 1 -> K bf16, 2 -> V^T bf16 (masked)
// mode 1 epilogue: fp32 row-major
#define BN 128
#define BK 32

template <int BMT>
__global__ __launch_bounds__(256) void gemm_mfma(
    const short* __restrict__ A,
    const short* __restrict__ W0, const float* __restrict__ b0,
    const short* __restrict__ W1, const float* __restrict__ b1,
    const short* __restrict__ W2, const float* __restrict__ b2,
    const int* __restrict__ mask,
    short* __restrict__ Qb, short* __restrict__ Kb, short* __restrict__ Vtb,
    float* __restrict__ outf, int mode)
{
    constexpr int MI = BMT / 32;
    __shared__ __align__(16) short As[BMT * BK];
    __shared__ __align__(16) short Bs[BN * BK];

    const int tid  = threadIdx.x;
    const int wave = tid >> 6;
    const int lane = tid & 63;
    const int quad = lane >> 4;
    const int l16  = lane & 15;
    const int wm   = wave >> 1;
    const int wn   = wave & 1;

    const int m0   = blockIdx.y * BMT;
    const int n0   = blockIdx.x * BN;
    const int widx = n0 >> 10;
    const int nl0  = n0 & 1023;

    const short* Wp   = widx == 0 ? W0 : (widx == 1 ? W1 : W2);
    const float* bias = widx == 0 ? b0 : (widx == 1 ? b1 : b2);

    f4 acc[MI][4];
    #pragma unroll
    for (int i = 0; i < MI; i++)
        #pragma unroll
        for (int j = 0; j < 4; j++) {
            acc[i][j][0] = 0.f; acc[i][j][1] = 0.f;
            acc[i][j][2] = 0.f; acc[i][j][3] = 0.f;
        }

    const int K = Dn;
    const int lrow = tid >> 2;
    const int lkc  = ((tid & 3) ^ ((tid >> 4) & 3)) * 8;
    const short* Ar = A  + (size_t)(m0  + lrow) * K + lkc;
    const short* Br = Wp + (size_t)(nl0 + lrow) * K + lkc;

    const int sw = (l16 >> 2) & 3;
    const int ca = ((quad ^ sw) * 8);

    for (int k0 = 0; k0 < K; k0 += BK) {
        __syncthreads();
        GLOAD(Ar + k0, &As[wave * 512]);
        if constexpr (BMT == 128)
            GLOAD(Ar + (size_t)64 * K + k0, &As[2048 + wave * 512]);
        GLOAD(Br + k0, &Bs[wave * 512]);
        GLOAD(Br + (size_t)64 * K + k0, &Bs[2048 + wave * 512]);
        __syncthreads();

        frag16 a[MI], b[4];
        #pragma unroll
        for (int mi = 0; mi < MI; mi++)
            a[mi] = *(const frag16*)&As[(wm * (BMT / 2) + mi * 16 + l16) * BK + ca];
        #pragma unroll
        for (int ni = 0; ni < 4; ni++)
            b[ni] = *(const frag16*)&Bs[(wn * 64 + ni * 16 + l16) * BK + ca];
        #pragma unroll
        for (int mi = 0; mi < MI; mi++)
            #pragma unroll
            for (int ni = 0; ni < 4; ni++)
                acc[mi][ni] = __builtin_amdgcn_mfma_f32_16x16x32_f16(
                    a[mi], b[ni], acc[mi][ni], 0, 0, 0);
    }

    const float QSCALE = 0.125f * 1.44269504088896340736f;

    #pragma unroll
    for (int mi = 0; mi < MI; mi++) {
        #pragma unroll
        for (int ni = 0; ni < 4; ni++) {
            int nl = nl0 + wn * 64 + ni * 16 + l16;
            float bv = bias[nl];
            #pragma unroll
            for (int r = 0; r < 4; r++) {
                int m = m0 + wm * (BMT / 2) + mi * 16 + quad * 4 + r;
                float v = acc[mi][ni][r] + bv;
                if (mode == 0) {
                    int b  = m >> 11, s = m & (Sn - 1);
                    int h  = nl >> 6, dk = nl & 63;
                    if (widx == 0)
                        Qb[((size_t)(b * Hn + h) * Sn + s) * DKn + dk] = f2bf(v * QSCALE);
                    else if (widx == 1)
                        Kb[((size_t)(b * Hn + h) * Sn + s) * DKn + dk] = f2bf(v);
                    else {
                        float mv = (float)mask[b * Sn + s];
                        Vtb[((size_t)(b * Hn + h) * DKn + dk) * Sn + s] = f2bf(v * mv);
                    }
                } else {
                    outf[(size_t)m * Dn + nl] = v;
                }
            }
        }
    }
}

// ---------------- Flash attention v3: 2 q-groups/wave, GLOAD+XOR-swizzle ----
// Block = 4 waves, 128 q-rows (32/wave). K/V LDS packed 64x64 with 16B-chunk
// XOR swizzle chunk' = chunk ^ (row&7): staging via global_load_lds (per-lane
// swizzled source addr), all b128 frag reads <=2-way conflicts.
#define LP  72

__global__ __launch_bounds__(256) void attn_mfma(
    const short* __restrict__ Qb, const short* __restrict__ Kb,
    const short* __restrict__ Vtb, const short* __restrict__ mfb,
    short* __restrict__ ctxh)
{
    __shared__ __align__(16) short Ks[64 * 64];
    __shared__ __align__(16) short Vs[64 * 64];
    __shared__ short Ps[4][32 * LP];
    __shared__ __align__(16) short mfs[64];

    const int tid  = threadIdx.x;
    const int wave = tid >> 6;
    const int lane = tid & 63;
    const int quad = lane >> 4;
    const int l16  = lane & 15;

    const int qt  = blockIdx.x & 15;      // Sn/128 = 16 q-tiles
    const int bhh = blockIdx.x >> 4;
    const int b   = bhh >> 4;
    const int h   = bhh & 15;

    // Q fragments: 2 q-groups of 16 rows per wave
    fragb qf[2][2];
    #pragma unroll
    for (int w = 0; w < 2; w++) {
        int qrow = qt * 128 + wave * 32 + w * 16 + l16;
        const short* qptr = Qb + ((size_t)bhh * Sn + qrow) * DKn + quad * 8;
        qf[w][0] = *(const fragb*)(qptr);
        qf[w][1] = *(const fragb*)(qptr + 32);
    }

    f4 ctx[2][4];
    #pragma unroll
    for (int w = 0; w < 2; w++)
        #pragma unroll
        for (int dt = 0; dt < 4; dt++) {
            ctx[w][dt][0] = 0.f; ctx[w][dt][1] = 0.f;
            ctx[w][dt][2] = 0.f; ctx[w][dt][3] = 0.f;
        }
    f4 lacc[2];
    lacc[0][0] = 0.f; lacc[0][1] = 0.f; lacc[0][2] = 0.f; lacc[0][3] = 0.f;
    lacc[1] = lacc[0];

    // staging source offsets (shorts): lane l -> row l/8, src chunk (l%8)^(l/8)
    const int lr = lane >> 3;
    const int sc = ((lane & 7) ^ lr) * 8;
    const short* Kg = Kb  + (size_t)bhh * Sn * DKn;
    const short* Vg = Vtb + (size_t)bhh * DKn * Sn;
    const short* mg = mfb + (size_t)b * Sn;

    const short* Ksrc = Kg + (size_t)(wave * 16 + lr) * DKn + sc;  // + g*8*DKn + kt*4096
    const short* Vsrc = Vg + (size_t)(wave * 16 + lr) * Sn + sc;   // + g*8*Sn  + kt*64

    // read-side swizzled chunk offset (shorts); second half = ^32
    const int c0 = ((quad ^ (l16 & 7)) * 8);

    for (int kt = 0; kt < Sn / 64; kt++) {
        __syncthreads();
        GLOAD(Ksrc + (size_t)kt * 4096,             &Ks[(wave * 16) * 64]);
        GLOAD(Ksrc + (size_t)kt * 4096 + 8 * DKn,   &Ks[(wave * 16 + 8) * 64]);
        GLOAD(Vsrc + (size_t)kt * 64,               &Vs[(wave * 16) * 64]);
        GLOAD(Vsrc + (size_t)kt * 64 + 8 * Sn,      &Vs[(wave * 16 + 8) * 64]);
        if (tid < 8)
            *(uint4*)&mfs[tid * 8] = *(const uint4*)(mg + kt * 64 + tid * 8);
        __syncthreads();

        // ---- S^T: per t, K frags shared across both q-groups
        #pragma unroll
        for (int t = 0; t < 4; t++) {
            fragb k0 = *(const fragb*)&Ks[(t * 16 + l16) * 64 + c0];
            fragb k1 = *(const fragb*)&Ks[(t * 16 + l16) * 64 + (c0 ^ 32)];
            #pragma unroll
            for (int w = 0; w < 2; w++) {
                f4 a; a[0] = 0.f; a[1] = 0.f; a[2] = 0.f; a[3] = 0.f;
                a = __builtin_amdgcn_mfma_f32_16x16x32_bf16(k0, qf[w][0], a, 0, 0, 0);
                a = __builtin_amdgcn_mfma_f32_16x16x32_bf16(k1, qf[w][1], a, 0, 0, 0);
                unsigned u0 = __float_as_uint(exp2f(a[0]));
                unsigned u1 = __float_as_uint(exp2f(a[1]));
                unsigned u2 = __float_as_uint(exp2f(a[2]));
                unsigned u3 = __float_as_uint(exp2f(a[3]));
                uint2 pw;
                pw.x = __builtin_amdgcn_perm(u1, u0, 0x07060302u);
                pw.y = __builtin_amdgcn_perm(u3, u2, 0x07060302u);
                *(uint2*)&Ps[wave][(w * 16 + l16) * LP + 16 * t + quad * 4] = pw;
            }
        }

        // ---- PV + l accumulation (V/mask frags shared across q-groups)
        fragb p[2][2];
        #pragma unroll
        for (int w = 0; w < 2; w++) {
            p[w][0] = *(const fragb*)&Ps[wave][(w * 16 + l16) * LP + quad * 8];
            p[w][1] = *(const fragb*)&Ps[wave][(w * 16 + l16) * LP + quad * 8 + 32];
        }
        fragb m0 = *(const fragb*)&mfs[quad * 8];
        fragb m1 = *(const fragb*)&mfs[quad * 8 + 32];
        #pragma unroll
        for (int w = 0; w < 2; w++) {
            lacc[w] = __builtin_amdgcn_mfma_f32_16x16x32_bf16(p[w][0], m0, lacc[w], 0, 0, 0);
            lacc[w] = __builtin_amdgcn_mfma_f32_16x16x32_bf16(p[w][1], m1, lacc[w], 0, 0, 0);
        }
        #pragma unroll
        for (int dt = 0; dt < 4; dt++) {
            fragb v0 = *(const fragb*)&Vs[(dt * 16 + l16) * 64 + c0];
            fragb v1 = *(const fragb*)&Vs[(dt * 16 + l16) * 64 + (c0 ^ 32)];
            #pragma unroll
            for (int w = 0; w < 2; w++) {
                ctx[w][dt] = __builtin_amdgcn_mfma_f32_16x16x32_bf16(p[w][0], v0, ctx[w][dt], 0, 0, 0);
                ctx[w][dt] = __builtin_amdgcn_mfma_f32_16x16x32_bf16(p[w][1], v1, ctx[w][dt], 0, 0, 0);
            }
        }
    }

    // ---- epilogue
    #pragma unroll
    for (int w = 0; w < 2; w++)
        #pragma unroll
        for (int r = 0; r < 4; r++) {
            float inv = 1.f / lacc[w][r];
            int row = qt * 128 + wave * 32 + w * 16 + quad * 4 + r;
            #pragma unroll
            for (int dt = 0; dt < 4; dt++) {
                float val = ctx[w][dt][r] * inv;
                size_t idx = ((size_t)(b * Sn + row)) * Dn + h * DKn + dt * 16 + l16;
                ctxh[idx] = f2h(val);
            }
        }
}

// ---------------- launch ----------------
extern "C" void kernel_launch(void* const* d_in, const int* in_sizes, int n_in,
                              void* d_out, int out_size, void* d_ws, size_t ws_size,
                              hipStream_t stream) {
    const float* x    = (const float*)d_in[0];
    const int*   mask = (const int*)d_in[1];
    const float* Wq   = (const float*)d_in[2];
    const float* bq   = (const float*)d_in[3];
    const float* Wk   = (const float*)d_in[4];
    const float* bk   = (const float*)d_in[5];
    const float* Wv   = (const float*)d_in[6];
    const float* bv   = (const float*)d_in[7];
    const float* Wo   = (const float*)d_in[8];
    const float* bo   = (const float*)d_in[9];
    float* out = (float*)d_out;

    char* ws = (char*)d_ws;
    const size_t MB = 1024u * 1024u;
    short* xh  = (short*)(ws + 0 * MB);
    short* Wqh = (short*)(ws + 8 * MB);
    short* Wkh = (short*)(ws + 10 * MB);
    short* Wvh = (short*)(ws + 12 * MB);
    short* Woh = (short*)(ws + 14 * MB);
    short* Qb  = (short*)(ws + 16 * MB);
    short* Kb  = (short*)(ws + 24 * MB);
    short* Vtb = (short*)(ws + 32 * MB);
    short* Ch  = (short*)(ws + 40 * MB);
    short* mfb = (short*)(ws + 48 * MB);

    const int TOT = NX + 4 * NW + Bn * Sn;
    prep<<<(TOT + 255) / 256, 256, 0, stream>>>(
        x, Wq, Wk, Wv, Wo, mask, xh, Wqh, Wkh, Wvh, Woh, mfb);

    gemm_mfma<128><<<dim3(24, 32), 256, 0, stream>>>(
        xh, Wqh, bq, Wkh, bk, Wvh, bv, mask,
        Qb, Kb, Vtb, nullptr, 0);

    attn_mfma<<<dim3(Bn * Hn * (Sn / 128)), 256, 0, stream>>>(
        Qb, Kb, Vtb, mfb, Ch);

    gemm_mfma<64><<<dim3(8, 64), 256, 0, stream>>>(
        Ch, Woh, bo, Woh, bo, Woh, bo, mask,
        nullptr, nullptr, nullptr, out, 1);
}